// Round 5
// baseline (1652.449 us; speedup 1.0000x reference)
//
#include <hip/hip_runtime.h>

#define N_NODES_C 50000
#define N_EDGES_C 800000
#define N_EDGES2_C (2 * N_EDGES_C)
#define D 128
#define NBUCK 2000
#define RPB 25  // rows per bucket; NBUCK * RPB == N_NODES_C

static __device__ __forceinline__ unsigned short f2bf(float f) {
  unsigned u = __float_as_uint(f);
  u += 0x7fff + ((u >> 16) & 1);  // round-to-nearest-even
  return (unsigned short)(u >> 16);
}
static __device__ __forceinline__ float bf_lo(unsigned u) {
  return __uint_as_float(u << 16);
}
static __device__ __forceinline__ float bf_hi(unsigned u) {
  return __uint_as_float(u & 0xffff0000u);
}

// ---------------------------------------------------------------------------
// Kernel 1: alpha[i] = sigmoid(dot(x[i], alpha_w) + alpha_b), wave per node.
// ---------------------------------------------------------------------------
__global__ __launch_bounds__(256) void alpha_kernel(
    const float* __restrict__ x,
    const float* __restrict__ aw,
    const float* __restrict__ ab,
    float* __restrict__ alpha_out,
    float* __restrict__ alpha_ws,
    int n) {
  int wave = (int)((blockIdx.x * blockDim.x + threadIdx.x) >> 6);
  int lane = threadIdx.x & 63;
  if (wave >= n) return;
  const float* xr = x + (size_t)wave * D;
  float s = xr[lane] * aw[lane] + xr[lane + 64] * aw[lane + 64];
  #pragma unroll
  for (int off = 32; off > 0; off >>= 1)
    s += __shfl_down(s, off);
  if (lane == 0) {
    float a = 1.0f / (1.0f + __expf(-(s + ab[0])));
    alpha_out[wave] = a;
    alpha_ws[wave] = a;
  }
}

// ---------------------------------------------------------------------------
// Kernel 2: coarse-bucket histogram (2000 buckets of 25 rows).
// ---------------------------------------------------------------------------
__global__ __launch_bounds__(256) void hist_kernel(
    const int* __restrict__ lp_rows,
    const int* __restrict__ hp_rows,
    int* __restrict__ cnt) {
  int e = blockIdx.x * 256 + threadIdx.x;
  if (e >= N_EDGES2_C) return;
  int r = (e < N_EDGES_C) ? lp_rows[e] : hp_rows[e - N_EDGES_C];
  atomicAdd(&cnt[r / RPB], 1);
}

// ---------------------------------------------------------------------------
// Kernel 3: single-block scan of cnt[2000] -> start[] (exclusive) + cursor.
// Hillis-Steele over 2048 in LDS, 1024 threads x 2 elements.
// ---------------------------------------------------------------------------
__global__ __launch_bounds__(1024) void scan_kernel(
    const int* __restrict__ cnt,
    int* __restrict__ start,
    int* __restrict__ cursor) {
  __shared__ int s[2048];
  int t = threadIdx.x;
  s[t] = (t < NBUCK) ? cnt[t] : 0;
  s[t + 1024] = (t + 1024 < NBUCK) ? cnt[t + 1024] : 0;
  __syncthreads();
  for (int off = 1; off < 2048; off <<= 1) {
    int a = (t >= off) ? s[t - off] : 0;
    int b2 = (t + 1024 >= off) ? s[t + 1024 - off] : 0;
    __syncthreads();
    s[t] += a;
    s[t + 1024] += b2;
    __syncthreads();
  }
  int e0 = (t == 0) ? 0 : s[t - 1];
  if (t < NBUCK) { start[t] = e0; cursor[t] = e0; }
  int i2 = t + 1024;
  if (i2 < NBUCK) { int e1 = s[i2 - 1]; start[i2] = e1; cursor[i2] = e1; }
  if (t == 0) start[NBUCK] = s[NBUCK - 1];
}

// ---------------------------------------------------------------------------
// Kernel 4: coarse scatter. Cursor-allocated positions are sequential in
// arrival order -> only 2000 hot lines (128 KB) -> dense L2 writebacks.
// Pack (row:16 | col:16, gate-scaled val) in 8 B.
// ---------------------------------------------------------------------------
__global__ __launch_bounds__(256) void fill_kernel(
    const int* __restrict__ lp_rows, const int* __restrict__ lp_cols,
    const float* __restrict__ lp_vals,
    const int* __restrict__ hp_rows, const int* __restrict__ hp_cols,
    const float* __restrict__ hp_vals,
    const float* __restrict__ alpha,
    int* __restrict__ cursor,
    int2* __restrict__ pairs) {
  int e = blockIdx.x * 256 + threadIdx.x;
  if (e >= N_EDGES2_C) return;
  int r, c;
  float v;
  if (e < N_EDGES_C) {
    r = lp_rows[e];
    c = lp_cols[e];
    v = lp_vals[e] * alpha[r];
  } else {
    int i = e - N_EDGES_C;
    r = hp_rows[i];
    c = hp_cols[i];
    v = hp_vals[i] * (1.0f - alpha[r]);
  }
  int p = atomicAdd(&cursor[r / RPB], 1);
  pairs[p] = make_int2((int)(((unsigned)r << 16) | (unsigned)c),
                       __float_as_int(v));
}

// ---------------------------------------------------------------------------
// Kernel 5: gemm_y: y = x @ W^T, stored bf16. W in LDS, 64 nodes/block.
// ---------------------------------------------------------------------------
#define GNODES 64
#define GP 16
#define LDP 132

__global__ __launch_bounds__(256) void gemm_y_kernel(
    const float* __restrict__ x,
    const float* __restrict__ W,
    unsigned short* __restrict__ y,
    int n) {
  __shared__ float wt[D][LDP];
  __shared__ float zs[GP][LDP];

  int t = threadIdx.x;
  int node0 = blockIdx.x * GNODES;

  #pragma unroll
  for (int it = 0; it < 16; ++it) {
    int f = t + it * 256;
    int j = f >> 5;
    int k4 = f & 31;
    *(float4*)&wt[j][k4 * 4] = ((const float4*)W)[f];
  }

  int tj = t & 31;
  int ns = t >> 5;

  for (int p = 0; p < 4; ++p) {
    int nb = node0 + p * GP;
    __syncthreads();
    #pragma unroll
    for (int it = 0; it < 2; ++it) {
      int f = t + it * 256;
      int r = f >> 5;
      int c4 = f & 31;
      int node = nb + r;
      float4 v = make_float4(0.f, 0.f, 0.f, 0.f);
      if (node < n) v = ((const float4*)(x + (size_t)node * D))[c4];
      *(float4*)&zs[r][c4 * 4] = v;
    }
    __syncthreads();

    float acc[2][4] = {};
    #pragma unroll 4
    for (int k = 0; k < D; k += 4) {
      float4 w0 = *(const float4*)&wt[tj * 4 + 0][k];
      float4 w1 = *(const float4*)&wt[tj * 4 + 1][k];
      float4 w2 = *(const float4*)&wt[tj * 4 + 2][k];
      float4 w3 = *(const float4*)&wt[tj * 4 + 3][k];
      float4 z0 = *(const float4*)&zs[ns * 2 + 0][k];
      float4 z1 = *(const float4*)&zs[ns * 2 + 1][k];
      acc[0][0] += z0.x * w0.x + z0.y * w0.y + z0.z * w0.z + z0.w * w0.w;
      acc[0][1] += z0.x * w1.x + z0.y * w1.y + z0.z * w1.z + z0.w * w1.w;
      acc[0][2] += z0.x * w2.x + z0.y * w2.y + z0.z * w2.z + z0.w * w2.w;
      acc[0][3] += z0.x * w3.x + z0.y * w3.y + z0.z * w3.z + z0.w * w3.w;
      acc[1][0] += z1.x * w0.x + z1.y * w0.y + z1.z * w0.z + z1.w * w0.w;
      acc[1][1] += z1.x * w1.x + z1.y * w1.y + z1.z * w1.z + z1.w * w1.w;
      acc[1][2] += z1.x * w2.x + z1.y * w2.y + z1.z * w2.z + z1.w * w2.w;
      acc[1][3] += z1.x * w3.x + z1.y * w3.y + z1.z * w3.z + z1.w * w3.w;
    }

    #pragma unroll
    for (int ii = 0; ii < 2; ++ii) {
      int node = nb + ns * 2 + ii;
      if (node < n) {
        ushort4 o;
        o.x = f2bf(acc[ii][0]);
        o.y = f2bf(acc[ii][1]);
        o.z = f2bf(acc[ii][2]);
        o.w = f2bf(acc[ii][3]);
        *(ushort4*)&y[(size_t)node * D + tj * 4] = o;
      }
    }
  }
}

// ---------------------------------------------------------------------------
// Kernel 6: fused gather. One wave per bucket owns 25 rows exclusively in a
// private LDS fp32 accumulator. Per edge: broadcast pair, coalesced bf16x2
// y-row load, two fire-and-forget ds_add_f32 (no RMW dependency chain).
// Epilogue fuses bias + ReLU and writes out once. No global atomics.
// ---------------------------------------------------------------------------
__global__ __launch_bounds__(256) void gather_kernel(
    const int* __restrict__ start,
    const int2* __restrict__ pairs,
    const unsigned* __restrict__ y,   // [N][64] uints (bf16x2)
    const float* __restrict__ bias,
    float* __restrict__ out) {
  __shared__ float acc[4][RPB][D];  // 4 * 25 * 128 * 4 = 51200 B
  int w = threadIdx.x >> 6;
  int lane = threadIdx.x & 63;
  int B = blockIdx.x * 4 + w;
  int row0 = B * RPB;

  // Zero this wave's private accumulator (float2 -> 2-way bank alias, free).
  #pragma unroll
  for (int r = 0; r < RPB; ++r)
    *(float2*)&acc[w][r][lane * 2] = make_float2(0.f, 0.f);

  int b = start[B];
  int e = start[B + 1];
  #pragma unroll 2
  for (int p = b; p < e; ++p) {
    int2 pr = pairs[p];  // wave-uniform broadcast load
    unsigned rc = (unsigned)pr.x;
    float v = __int_as_float(pr.y);
    int c = (int)(rc & 0xffffu);
    int lr = (int)(rc >> 16) - row0;
    unsigned u = y[(size_t)c * 64 + lane];
    atomicAdd(&acc[w][lr][lane * 2], v * bf_lo(u));
    atomicAdd(&acc[w][lr][lane * 2 + 1], v * bf_hi(u));
  }
  __syncthreads();  // drain LDS atomics before reading back

  float2 bv = *(const float2*)&bias[lane * 2];
  #pragma unroll
  for (int r = 0; r < RPB; ++r) {
    int row = row0 + r;
    float2 a2 = *(const float2*)&acc[w][r][lane * 2];
    float2 o;
    o.x = fmaxf(a2.x + bv.x, 0.0f);
    o.y = fmaxf(a2.y + bv.y, 0.0f);
    *(float2*)&out[(size_t)row * D + lane * 2] = o;
  }
}

extern "C" void kernel_launch(void* const* d_in, const int* in_sizes, int n_in,
                              void* d_out, int out_size, void* d_ws, size_t ws_size,
                              hipStream_t stream) {
  const float* x = (const float*)d_in[0];
  const int* lp_rows = (const int*)d_in[1];
  const int* lp_cols = (const int*)d_in[2];
  const float* lp_vals = (const float*)d_in[3];
  const int* hp_rows = (const int*)d_in[4];
  const int* hp_cols = (const int*)d_in[5];
  const float* hp_vals = (const float*)d_in[6];
  const float* alpha_w = (const float*)d_in[7];
  const float* alpha_b = (const float*)d_in[8];
  const float* W = (const float*)d_in[9];
  const float* bias = (const float*)d_in[10];

  float* out = (float*)d_out;                      // [N, 128]
  float* alpha_out = out + (size_t)N_NODES_C * D;  // [N, 1] output tail

  // Workspace carve-up (all 256B-aligned):
  char* ws = (char*)d_ws;
  unsigned short* y = (unsigned short*)ws;
  ws += (size_t)N_NODES_C * D * 2;                 // 12.8 MB bf16 y
  float* alpha_ws = (float*)ws;          ws += 200192;
  int* cnt = (int*)ws;                   ws += 8192;   // 2000 i
  int* start = (int*)ws;                 ws += 8192;   // 2001 i
  int* cursor = (int*)ws;                ws += 8192;   // 2000 i
  int2* pairs = (int2*)ws;               ws += (size_t)N_EDGES2_C * 8;  // 12.8 MB

  hipMemsetAsync(cnt, 0, NBUCK * sizeof(int), stream);

  alpha_kernel<<<(N_NODES_C + 3) / 4, 256, 0, stream>>>(
      x, alpha_w, alpha_b, alpha_out, alpha_ws, N_NODES_C);

  hist_kernel<<<(N_EDGES2_C + 255) / 256, 256, 0, stream>>>(
      lp_rows, hp_rows, cnt);

  scan_kernel<<<1, 1024, 0, stream>>>(cnt, start, cursor);

  fill_kernel<<<(N_EDGES2_C + 255) / 256, 256, 0, stream>>>(
      lp_rows, lp_cols, lp_vals, hp_rows, hp_cols, hp_vals,
      alpha_ws, cursor, pairs);

  gemm_y_kernel<<<(N_NODES_C + GNODES - 1) / GNODES, 256, 0, stream>>>(
      x, W, y, N_NODES_C);

  gather_kernel<<<NBUCK / 4, 256, 0, stream>>>(
      start, pairs, (const unsigned*)y, bias, out);
}